// Round 14
// baseline (720.821 us; speedup 1.0000x reference)
//
#include <hip/hip_runtime.h>
#include <hip/hip_bf16.h>

#define DEVFN __device__ __forceinline__

typedef __attribute__((ext_vector_type(8))) short bf16x8;
typedef __attribute__((ext_vector_type(4))) float f32x4;

constexpr int T = 128, C = 8, K = 9;
constexpr int HW = 1024;   // 32x32
constexpr int BT = 512;    // B*T images
constexpr size_t Z_SIZE = (size_t)BT * C * HW;

constexpr int SR = 34 * 128;        // 4352 B per site-row
constexpr int TILE64 = 10 * SR;     // conv_final tile
constexpr int SROW32 = 34 * 64;
constexpr int TILE32 = 10 * SROW32; // conv_in tile

// fragment-packed weights (bf16 element offsets): [tap][c][mt][lane][8]
constexpr int WP_IN = 0;
constexpr int WP_W1_0 = 18432;
constexpr int WP_W2_0 = 55296;
constexpr int WP_W1_1 = 92160;
constexpr int WP_W2_1 = 129024;
constexpr int WP_OUT = 165888;
constexpr int WP_TOT = 175104;

DEVFN ushort f2bs(float x) {
  __hip_bfloat16 h = __float2bfloat16(x);
  ushort u;
  __builtin_memcpy(&u, &h, 2);
  return u;
}
DEVFN float bs2f(ushort u) {
  __hip_bfloat16 h;
  __builtin_memcpy(&h, &u, 2);
  return __bfloat162float(h);
}

DEVFN void interp_params(const int* __restrict__ idx, int b, int t,
                         int& t0, int& t1, float& ar, float& a) {
  const int* ib = idx + b * K;
  int cnt = 0;
#pragma unroll
  for (int k = 0; k < K; ++k) cnt += (ib[k] <= t) ? 1 : 0;
  int seg = min(max(cnt - 1, 0), K - 2);
  t0 = ib[seg];
  t1 = ib[seg + 1];
  ar = (float)(t - t0) / (float)max(t1 - t0, 1);
  a = fminf(fmaxf(ar, 0.f), 1.f);
}

// ---------------------------------------------------------------------------
__global__ __launch_bounds__(256) void pack_weights(
    const float* __restrict__ w_in, const float* __restrict__ w1s,
    const float* __restrict__ w2s, const float* __restrict__ w_out,
    __hip_bfloat16* __restrict__ wp) {
  int e = blockIdx.x * 256 + threadIdx.x;
  if (e >= WP_TOT) return;
  float v;
  if (e < WP_W1_0) {
    int tap = e / 2048;
    int r2 = e % 2048;
    int mt = r2 / 512;
    int lane = (r2 / 8) & 63;
    int el = e & 7;
    int oc = mt * 16 + (lane & 15);
    int ic = (lane >> 4) * 8 + el;
    v = (ic < 25) ? w_in[((size_t)oc * 25 + ic) * 9 + tap] : 0.f;
  } else if (e < WP_OUT) {
    int r = e - WP_W1_0;
    int layer = r / 36864;  // 0:w1b0 1:w2b0 2:w1b1 3:w2b1
    int r2 = r % 36864;
    int tap = r2 / 4096;
    int c = (r2 / 2048) & 1;
    int mt = (r2 / 512) & 3;
    int lane = (r2 / 8) & 63;
    int el = r2 & 7;
    int oc = mt * 16 + (lane & 15);
    int ic = c * 32 + (lane >> 4) * 8 + el;
    const float* src = (layer & 1) ? w2s : w1s;
    int blk = layer >> 1;
    v = src[(((size_t)blk * 64 + oc) * 64 + ic) * 9 + tap];
  } else {
    int r2 = e - WP_OUT;
    int tap = r2 / 1024;
    int c = (r2 / 512) & 1;
    int lane = (r2 / 8) & 63;
    int el = r2 & 7;
    int oc = lane & 15;
    int ic = c * 32 + (lane >> 4) * 8 + el;
    v = (oc < 9) ? w_out[((size_t)oc * 64 + ic) * 9 + tap] : 0.f;
  }
  wp[e] = __float2bfloat16(v);
}

// ---------------------------------------------------------------------------
// fused residual block v2: out = in + conv2(silu(conv1(in)+b1)) + b2.
// grid (BT, 4) 8-row chunks; 256 thr (4 waves); LDS = hT(12 rows) + uT(6 ring)
// = 78336 B -> 2 blocks/CU. h-tile stays intact until its readers finish, so
// the residual is read directly from hT (no register capture, no stagger).
// Phase ledger (R/W per region, barrier-separated):
//  S  : W hT (stage rows R0-2..R0+9), W uT halo cols     | B1
//  C1a: R hT -> W uT slots 0..5 (u rows -1..4, wv<3)     | B2
//  C2a: R uT 0..5 + R hT(resid s4,5? no: s2..5) -> regs  | B3
//  W2a: W hT scratch site-rows 0..3 (dead after C2a)     | B4
//  STa: R hT 0..3 -> global rows R0..R0+3; wv>=2: C1b    | B5
//       (C1b: R hT 6..11 -> W uT slots 0..3)
//  C2b: R uT + R hT(resid s6..9) -> regs                 | B6
//  W2b: W hT scratch 0..3                                | B7
//  STb: R hT 0..3 -> global rows R0+4..R0+7
// ---------------------------------------------------------------------------
__global__ __launch_bounds__(256) void fused_rb2(
    const __hip_bfloat16* __restrict__ in,   // h  [512][1024][64]
    const __hip_bfloat16* __restrict__ wp1,  // [9][2][4][64][8]
    const __hip_bfloat16* __restrict__ wp2,
    const float* __restrict__ b1, const float* __restrict__ b2,
    __hip_bfloat16* __restrict__ out) {      // h_new
  __shared__ __align__(16) char hT[12 * SR];  // 52224
  __shared__ __align__(16) char uT[6 * SR];   // 26112

  const int img = blockIdx.x;
  const int R0 = blockIdx.y * 8;
  const int tid = threadIdx.x;
  const int lane = tid & 63, wv = tid >> 6, g = lane >> 4, ln = lane & 15;
  const size_t imgBase = (size_t)img * HW * 64;

  int base[3][2];
#pragma unroll
  for (int d = 0; d < 3; ++d)
#pragma unroll
    for (int c = 0; c < 2; ++c)
      base[d][c] = (((ln + d) * 128 + c * 64 + g * 16) ^ (((ln + d) & 7) << 4));
  const int wkey = ((ln + 1) & 7) << 4;
  int wbase[4];
#pragma unroll
  for (int mt = 0; mt < 4; ++mt)
    wbase[mt] = (ln + 1) * 128 + ((mt * 32 + g * 8) ^ wkey);

  // ---- S: stage h rows R0-2..R0+9 (zero outside image) ----
  for (int e = tid; e < 3264; e += 256) {
    int srow = e / 272;
    int rem = e - srow * 272;
    int sx = rem >> 3, slot = rem & 7;
    int gy = R0 - 2 + srow, gx = sx - 1;
    int4 v = int4{0, 0, 0, 0};
    if (((unsigned)gy < 32u) & ((unsigned)gx < 32u))
      v = *(const int4*)(in + imgBase + (size_t)(gy * 32 + gx) * 64 + slot * 8);
    int dst = (srow * 34 + sx) * 128 + ((slot * 16) ^ ((sx & 7) << 4));
    *(int4*)(hT + dst) = v;
  }
  // zero u-ring halo columns once (sites 0 and 33, all 6 slots)
  if (tid < 96) {
    int slot = tid >> 4, rem = tid & 15;
    int site = (rem >> 3) ? 33 : 0, q = rem & 7;
    *(int4*)(uT + slot * SR + site * 128 + q * 16) = int4{0, 0, 0, 0};
  }
  __syncthreads();  // B1

  // conv1 pair j: u rows 2j-1, 2j (R0-relative) from hT site-rows 2j..2j+3.
  auto conv1_pair = [&](int j) {
    f32x4 acc[4][4];
#pragma unroll
    for (int mt = 0; mt < 4; ++mt)
#pragma unroll
      for (int nt = 0; nt < 4; ++nt) acc[mt][nt] = (f32x4)0.f;
    const int rowOff = 2 * j * SR;
#pragma unroll
    for (int c = 0; c < 2; ++c)
#pragma unroll
      for (int d = 0; d < 3; ++d) {
        bf16x8 bv[4][2];
#pragma unroll
        for (int jj = 0; jj < 4; ++jj)
#pragma unroll
          for (int xh = 0; xh < 2; ++xh)
            bv[jj][xh] = *(const bf16x8*)(hT + rowOff + jj * SR + base[d][c] +
                                          xh * 2048);
#pragma unroll
        for (int mt = 0; mt < 4; ++mt)
#pragma unroll
          for (int dyi = 0; dyi < 3; ++dyi) {
            bf16x8 av = *(const bf16x8*)(wp1 +
                                         ((((dyi * 3 + d) * 2 + c) * 4 + mt) *
                                              64 +
                                          lane) *
                                             8);
#pragma unroll
            for (int oy = 0; oy < 2; ++oy)
#pragma unroll
              for (int xh = 0; xh < 2; ++xh)
                acc[mt][oy * 2 + xh] = __builtin_amdgcn_mfma_f32_16x16x32_bf16(
                    av, bv[oy + dyi][xh], acc[mt][oy * 2 + xh], 0, 0, 0);
          }
      }
    // write u rows (zero outside image: SAME padding for conv2)
#pragma unroll
    for (int oy = 0; oy < 2; ++oy) {
      const int urow = R0 + 2 * j - 1 + oy;
      const bool valid = (unsigned)urow < 32u;
      int slot = 2 * j + oy;
      if (slot >= 6) slot -= 6;
#pragma unroll
      for (int mt = 0; mt < 4; ++mt) {
        const float4 b4 = *(const float4*)(b1 + mt * 16 + g * 4);
#pragma unroll
        for (int xh = 0; xh < 2; ++xh) {
          ushort4 s = ushort4{0, 0, 0, 0};
          if (valid) {
            float v0 = acc[mt][oy * 2 + xh][0] + b4.x;
            float v1 = acc[mt][oy * 2 + xh][1] + b4.y;
            float v2 = acc[mt][oy * 2 + xh][2] + b4.z;
            float v3 = acc[mt][oy * 2 + xh][3] + b4.w;
            s.x = f2bs(v0 / (1.f + expf(-v0)));
            s.y = f2bs(v1 / (1.f + expf(-v1)));
            s.z = f2bs(v2 / (1.f + expf(-v2)));
            s.w = f2bs(v3 / (1.f + expf(-v3)));
          }
          *(ushort4*)(uT + slot * SR + xh * 2048 + wbase[mt]) = s;
        }
      }
    }
  };

  // conv2 unit (abs out pair p, xh): resid from hT site-rows 2p+2,2p+3;
  // taps from ring slots (2p+jj)%6. Result -> held (8 ushort4).
  auto conv2_unit = [&](int p, int xh, ushort4 (&held)[8]) {
    f32x4 acc[4][2];
#pragma unroll
    for (int mt = 0; mt < 4; ++mt)
#pragma unroll
      for (int oy = 0; oy < 2; ++oy) {
        ushort4 h4 = *(const ushort4*)(hT + (2 * p + 2 + oy) * SR + xh * 2048 +
                                       wbase[mt]);
        f32x4 a4;
        a4[0] = bs2f(h4.x);
        a4[1] = bs2f(h4.y);
        a4[2] = bs2f(h4.z);
        a4[3] = bs2f(h4.w);
        acc[mt][oy] = a4;
      }
#pragma unroll
    for (int c = 0; c < 2; ++c)
#pragma unroll
      for (int d = 0; d < 3; ++d) {
        bf16x8 bv[4];
#pragma unroll
        for (int jj = 0; jj < 4; ++jj) {
          int slot = 2 * p + jj;
          while (slot >= 6) slot -= 6;
          bv[jj] = *(const bf16x8*)(uT + slot * SR + base[d][c] + xh * 2048);
        }
#pragma unroll
        for (int mt = 0; mt < 4; ++mt)
#pragma unroll
          for (int dyi = 0; dyi < 3; ++dyi) {
            bf16x8 av = *(const bf16x8*)(wp2 +
                                         ((((dyi * 3 + d) * 2 + c) * 4 + mt) *
                                              64 +
                                          lane) *
                                             8);
#pragma unroll
            for (int oy = 0; oy < 2; ++oy)
              acc[mt][oy] = __builtin_amdgcn_mfma_f32_16x16x32_bf16(
                  av, bv[oy + dyi], acc[mt][oy], 0, 0, 0);
          }
      }
#pragma unroll
    for (int mt = 0; mt < 4; ++mt) {
      const float4 b4 = *(const float4*)(b2 + mt * 16 + g * 4);
#pragma unroll
      for (int oy = 0; oy < 2; ++oy) {
        ushort4 s;
        s.x = f2bs(acc[mt][oy][0] + b4.x);
        s.y = f2bs(acc[mt][oy][1] + b4.y);
        s.z = f2bs(acc[mt][oy][2] + b4.z);
        s.w = f2bs(acc[mt][oy][3] + b4.w);
        held[mt * 2 + oy] = s;
      }
    }
  };

  // scratch write: held -> hT site-rows 2*pl+oy (pl = phase-local pair 0,1)
  auto scratch_write = [&](const ushort4 (&held)[8], int pl, int xh) {
#pragma unroll
    for (int mt = 0; mt < 4; ++mt)
#pragma unroll
      for (int oy = 0; oy < 2; ++oy)
        *(ushort4*)(hT + (2 * pl + oy) * SR + xh * 2048 + wbase[mt]) =
            held[mt * 2 + oy];
  };

  // coalesced store: scratch site-rows 0..3 -> global rows R0+ch*4..+3
  auto store4 = [&](int ch) {
    const int row = tid >> 6;          // 0..3
    const int rem = tid & 63;
    const int px = rem >> 1, half = rem & 1;
    const int sx = px + 1;
    const int key = (sx & 7) << 4;
    const char* sp = hT + row * SR + sx * 128;
    int4 v[4];
#pragma unroll
    for (int q = 0; q < 4; ++q)
      v[q] = *(const int4*)(sp + (((half * 4 + q) * 16) ^ key));
    const int grow = R0 + ch * 4 + row;
    char* op = (char*)(out + imgBase + (size_t)(grow * 32 + px) * 64 +
                       half * 32);
#pragma unroll
    for (int q = 0; q < 4; ++q) *(int4*)(op + q * 16) = v[q];
  };

  ushort4 held[8];

  // C1a: u pairs 0..2 (rows -1..4) -> ring slots 0..5
  if (wv < 3) conv1_pair(wv);
  __syncthreads();  // B2

  // C2a: out pairs 0,1
  conv2_unit(wv >> 1, wv & 1, held);
  __syncthreads();  // B3
  scratch_write(held, wv >> 1, wv & 1);
  __syncthreads();  // B4

  // STa + C1b (u pairs 3,4 -> slots 0..3)
  store4(0);
  if (wv >= 2) conv1_pair(wv + 1);  // wv=2 -> pair 3, wv=3 -> pair 4
  __syncthreads();  // B5

  // C2b: out pairs 2,3
  conv2_unit(2 + (wv >> 1), wv & 1, held);
  __syncthreads();  // B6
  scratch_write(held, wv >> 1, wv & 1);
  __syncthreads();  // B7
  store4(1);
}

// ---------------------------------------------------------------------------
// conv_in: prep fused into staging (round-8 proven). grid (BT,4), 256 thr.
// ---------------------------------------------------------------------------
__global__ __launch_bounds__(256) void conv_in_t(
    const float* __restrict__ latents, const int* __restrict__ idx,
    const __hip_bfloat16* __restrict__ wpf, const float* __restrict__ bias,
    __hip_bfloat16* __restrict__ out) {
  __shared__ __align__(16) char sBuf[TILE32];

  const int img = blockIdx.x;
  const int R0 = blockIdx.y * 8;
  const int tid = threadIdx.x;
  const int lane = tid & 63, wv = tid >> 6, g = lane >> 4, ln = lane & 15;
  const int r0L = wv * 2;
  const int b = img >> 7, t = img & 127;

  int t0, t1;
  float ar, a;
  interp_params(idx, b, t, t0, t1, ar, a);
  const float* z0p = latents + ((size_t)b * T + t0) * C * HW;
  const float* z1p = latents + ((size_t)b * T + t1) * C * HW;
  const ushort ab = f2bs(a);

  for (int e = tid; e < 340; e += 256) {
    int srow = e / 34, sx = e - srow * 34;
    int gy = R0 - 1 + srow, gx = sx - 1;
    char* sp = sBuf + srow * SROW32 + sx * 64;
    const int key = (sx & 3) << 4;
    if (((unsigned)gy < 32u) & ((unsigned)gx < 32u)) {
      int p = gy * 32 + gx;
      float v0[8], v1[8];
#pragma unroll
      for (int c2 = 0; c2 < 8; ++c2) {
        v0[c2] = z0p[c2 * HW + p];
        v1[c2] = z1p[c2 * HW + p];
      }
      ushort u[8];
      int4 q;
#pragma unroll
      for (int c2 = 0; c2 < 8; ++c2) u[c2] = f2bs((1.f - a) * v0[c2] + a * v1[c2]);
      q.x = (int)u[0] | ((int)u[1] << 16); q.y = (int)u[2] | ((int)u[3] << 16);
      q.z = (int)u[4] | ((int)u[5] << 16); q.w = (int)u[6] | ((int)u[7] << 16);
      *(int4*)(sp + (0 ^ key)) = q;
#pragma unroll
      for (int c2 = 0; c2 < 8; ++c2) u[c2] = f2bs(v0[c2]);
      q.x = (int)u[0] | ((int)u[1] << 16); q.y = (int)u[2] | ((int)u[3] << 16);
      q.z = (int)u[4] | ((int)u[5] << 16); q.w = (int)u[6] | ((int)u[7] << 16);
      *(int4*)(sp + (16 ^ key)) = q;
#pragma unroll
      for (int c2 = 0; c2 < 8; ++c2) u[c2] = f2bs(v1[c2]);
      q.x = (int)u[0] | ((int)u[1] << 16); q.y = (int)u[2] | ((int)u[3] << 16);
      q.z = (int)u[4] | ((int)u[5] << 16); q.w = (int)u[6] | ((int)u[7] << 16);
      *(int4*)(sp + (32 ^ key)) = q;
      q.x = (int)ab; q.y = 0; q.z = 0; q.w = 0;
      *(int4*)(sp + (48 ^ key)) = q;
    } else {
      int4 z = int4{0, 0, 0, 0};
#pragma unroll
      for (int sl = 0; sl < 4; ++sl) *(int4*)(sp + ((sl * 16) ^ key)) = z;
    }
  }
  __syncthreads();

  int base[3];
#pragma unroll
  for (int d = 0; d < 3; ++d)
    base[d] = r0L * SROW32 + (((ln + d) * 64 + g * 16) ^ (((ln + d) & 3) << 4));

  f32x4 acc[4][4];
#pragma unroll
  for (int mt = 0; mt < 4; ++mt)
#pragma unroll
    for (int nt = 0; nt < 4; ++nt) acc[mt][nt] = (f32x4)0.f;

#pragma unroll
  for (int d = 0; d < 3; ++d) {
    bf16x8 bv[4][2];
#pragma unroll
    for (int j = 0; j < 4; ++j)
#pragma unroll
      for (int xh = 0; xh < 2; ++xh)
        bv[j][xh] = *(const bf16x8*)(sBuf + base[d] + xh * 1024 + j * SROW32);
#pragma unroll
    for (int mt = 0; mt < 4; ++mt)
#pragma unroll
      for (int dyi = 0; dyi < 3; ++dyi) {
        const int tap = dyi * 3 + d;
        bf16x8 av = *(const bf16x8*)(wpf + ((tap * 4 + mt) * 64 + lane) * 8);
#pragma unroll
        for (int oy = 0; oy < 2; ++oy)
#pragma unroll
          for (int xh = 0; xh < 2; ++xh)
            acc[mt][oy * 2 + xh] = __builtin_amdgcn_mfma_f32_16x16x32_bf16(
                av, bv[oy + dyi][xh], acc[mt][oy * 2 + xh], 0, 0, 0);
      }
  }

  const size_t imgBase = (size_t)img * HW * 64;
#pragma unroll
  for (int mt = 0; mt < 4; ++mt) {
    const float4 bv4 = *(const float4*)(bias + mt * 16 + g * 4);
#pragma unroll
    for (int nt = 0; nt < 4; ++nt) {
      const int px = (R0 + r0L + (nt >> 1)) * 32 + (nt & 1) * 16 + ln;
      float v0 = acc[mt][nt][0] + bv4.x;
      float v1 = acc[mt][nt][1] + bv4.y;
      float v2 = acc[mt][nt][2] + bv4.z;
      float v3 = acc[mt][nt][3] + bv4.w;
      ushort4 sv;
      sv.x = f2bs(v0 / (1.f + expf(-v0)));
      sv.y = f2bs(v1 / (1.f + expf(-v1)));
      sv.z = f2bs(v2 / (1.f + expf(-v2)));
      sv.w = f2bs(v3 / (1.f + expf(-v3)));
      *(ushort4*)(out + imgBase + (size_t)px * 64 + mt * 16 + g * 4) = sv;
    }
  }
}

// ---------------------------------------------------------------------------
// final conv (64->16, 9 real) fused with z_hat / conf epilogue (round 8).
// ---------------------------------------------------------------------------
__global__ __launch_bounds__(256) void conv_final_t(
    const __hip_bfloat16* __restrict__ in, const __hip_bfloat16* __restrict__ wpf,
    const float* __restrict__ bias, const float* __restrict__ latents,
    const int* __restrict__ idx, float* __restrict__ dout) {
  __shared__ __align__(16) char sBuf[TILE64];
  __shared__ float sOut[256][17];

  const int img = blockIdx.x;
  const int R0 = blockIdx.y * 8;
  const int tid = threadIdx.x;
  const int lane = tid & 63, wv = tid >> 6, g = lane >> 4, ln = lane & 15;
  const int r0L = wv * 2;
  const int b = img >> 7, t = img & 127;
  const size_t imgBase = (size_t)img * HW * 64;

  int t0, t1;
  float ar, a;
  interp_params(idx, b, t, t0, t1, ar, a);
  const float* z0p = latents + ((size_t)b * T + t0) * C * HW;
  const float* z1p = latents + ((size_t)b * T + t1) * C * HW;

  for (int e = tid; e < 2720; e += 256) {
    int srow = e / 272;
    int rem = e - srow * 272;
    int sx = rem >> 3, slot = rem & 7;
    int gy = R0 - 1 + srow, gx = sx - 1;
    int4 v = int4{0, 0, 0, 0};
    if (((unsigned)gy < 32u) & ((unsigned)gx < 32u))
      v = *(const int4*)(in + imgBase + (size_t)(gy * 32 + gx) * 64 + slot * 8);
    int dst = (srow * 34 + sx) * 128 + ((slot * 16) ^ ((sx & 7) << 4));
    *(int4*)(sBuf + dst) = v;
  }
  __syncthreads();

  int base[3][2];
#pragma unroll
  for (int d = 0; d < 3; ++d)
#pragma unroll
    for (int c = 0; c < 2; ++c)
      base[d][c] = r0L * SR +
                   (((ln + d) * 128 + c * 64 + g * 16) ^ (((ln + d) & 7) << 4));

  f32x4 acc[4];
#pragma unroll
  for (int nt = 0; nt < 4; ++nt) acc[nt] = (f32x4)0.f;

#pragma unroll
  for (int c = 0; c < 2; ++c)
#pragma unroll
    for (int d = 0; d < 3; ++d) {
      bf16x8 bv[4][2];
#pragma unroll
      for (int j = 0; j < 4; ++j)
#pragma unroll
        for (int xh = 0; xh < 2; ++xh)
          bv[j][xh] = *(const bf16x8*)(sBuf + base[d][c] + xh * 2048 + j * SR);
#pragma unroll
      for (int dyi = 0; dyi < 3; ++dyi) {
        const int tap = dyi * 3 + d;
        bf16x8 av = *(const bf16x8*)(wpf + ((tap * 2 + c) * 64 + lane) * 8);
#pragma unroll
        for (int oy = 0; oy < 2; ++oy)
#pragma unroll
          for (int xh = 0; xh < 2; ++xh)
            acc[oy * 2 + xh] = __builtin_amdgcn_mfma_f32_16x16x32_bf16(
                av, bv[oy + dyi][xh], acc[oy * 2 + xh], 0, 0, 0);
      }
    }

#pragma unroll
  for (int nt = 0; nt < 4; ++nt) {
    const int pxl = (r0L + (nt >> 1)) * 32 + (nt & 1) * 16 + ln;
#pragma unroll
    for (int r = 0; r < 4; ++r) {
      const int oc = g * 4 + r;
      sOut[pxl][oc] = acc[nt][r] + ((oc < 9) ? bias[oc] : 0.f);
    }
  }
  __syncthreads();

  const bool interior = (ar > 0.f) && (ar < 1.f);
  const float aa = a * (1.f - a);
  const int px = R0 * 32 + tid;
#pragma unroll
  for (int c2 = 0; c2 < 8; ++c2) {
    float res = sOut[tid][c2];
    float v0 = z0p[c2 * HW + px], v1 = z1p[c2 * HW + px];
    float zb = (1.f - a) * v0 + a * v1;
    dout[((size_t)img * C + c2) * HW + px] = zb + aa * res;
  }
  float unc = 1.f / (1.f + expf(-sOut[tid][8]));
  float conf = interior ? fminf(fmaxf(1.f - unc, 0.f), 1.f) : 1.f;
  dout[Z_SIZE + (size_t)img * HW + px] = conf;
}

// ---------------------------------------------------------------------------
extern "C" void kernel_launch(void* const* d_in, const int* in_sizes, int n_in,
                              void* d_out, int out_size, void* d_ws,
                              size_t ws_size, hipStream_t stream) {
  const float* latents = (const float*)d_in[0];
  const int* idx = (const int*)d_in[1];
  const float* w_in = (const float*)d_in[2];
  const float* b_in = (const float*)d_in[3];
  const float* w1s = (const float*)d_in[4];
  const float* b1s = (const float*)d_in[5];
  const float* w2s = (const float*)d_in[6];
  const float* b2s = (const float*)d_in[7];
  const float* w_out = (const float*)d_in[8];
  const float* b_out = (const float*)d_in[9];
  float* dout = (float*)d_out;

  char* ws = (char*)d_ws;
  __hip_bfloat16* A = (__hip_bfloat16*)ws;                        // 64 MiB
  __hip_bfloat16* Bb = (__hip_bfloat16*)(ws + (size_t)67108864);  // 64 MiB
  __hip_bfloat16* wpk = (__hip_bfloat16*)(ws + (size_t)134217728);

  pack_weights<<<(WP_TOT + 255) / 256, 256, 0, stream>>>(w_in, w1s, w2s, w_out,
                                                         wpk);

  conv_in_t<<<dim3(BT, 4), 256, 0, stream>>>(latents, idx, wpk + WP_IN, b_in,
                                             A);

  fused_rb2<<<dim3(BT, 4), 256, 0, stream>>>(A, wpk + WP_W1_0, wpk + WP_W2_0,
                                             b1s, b2s, Bb);
  fused_rb2<<<dim3(BT, 4), 256, 0, stream>>>(Bb, wpk + WP_W1_1, wpk + WP_W2_1,
                                             b1s + 64, b2s + 64, A);

  conv_final_t<<<dim3(BT, 4), 256, 0, stream>>>(A, wpk + WP_OUT, b_out, latents,
                                                idx, dout);
}

// Round 15
// 405.180 us; speedup vs baseline: 1.7790x; 1.7790x over previous
//
#include <hip/hip_runtime.h>
#include <hip/hip_bf16.h>

#define DEVFN __device__ __forceinline__

typedef __attribute__((ext_vector_type(8))) short bf16x8;
typedef __attribute__((ext_vector_type(4))) float f32x4;

constexpr int T = 128, C = 8, K = 9;
constexpr int HW = 1024;   // 32x32
constexpr int BT = 512;    // B*T images
constexpr size_t Z_SIZE = (size_t)BT * C * HW;

constexpr int SR = 34 * 128;        // 4352 B per 64-ch site-row
constexpr int LTILE = 6 * SR;       // 26112 B lite conv64 tile -> 6 blocks/CU
constexpr int TILE64 = 10 * SR;     // conv_final tile
constexpr int SROW32 = 34 * 64;
constexpr int TILE32 = 10 * SROW32; // conv_in tile

// fragment-packed weights (bf16 element offsets): [tap][c][mt][lane][8]
constexpr int WP_IN = 0;
constexpr int WP_W1_0 = 18432;
constexpr int WP_W2_0 = 55296;
constexpr int WP_W1_1 = 92160;
constexpr int WP_W2_1 = 129024;
constexpr int WP_OUT = 165888;
constexpr int WP_TOT = 175104;

DEVFN ushort f2bs(float x) {
  __hip_bfloat16 h = __float2bfloat16(x);
  ushort u;
  __builtin_memcpy(&u, &h, 2);
  return u;
}
DEVFN float bs2f(ushort u) {
  __hip_bfloat16 h;
  __builtin_memcpy(&h, &u, 2);
  return __bfloat162float(h);
}

DEVFN void interp_params(const int* __restrict__ idx, int b, int t,
                         int& t0, int& t1, float& ar, float& a) {
  const int* ib = idx + b * K;
  int cnt = 0;
#pragma unroll
  for (int k = 0; k < K; ++k) cnt += (ib[k] <= t) ? 1 : 0;
  int seg = min(max(cnt - 1, 0), K - 2);
  t0 = ib[seg];
  t1 = ib[seg + 1];
  ar = (float)(t - t0) / (float)max(t1 - t0, 1);
  a = fminf(fmaxf(ar, 0.f), 1.f);
}

// ---------------------------------------------------------------------------
__global__ __launch_bounds__(256) void pack_weights(
    const float* __restrict__ w_in, const float* __restrict__ w1s,
    const float* __restrict__ w2s, const float* __restrict__ w_out,
    __hip_bfloat16* __restrict__ wp) {
  int e = blockIdx.x * 256 + threadIdx.x;
  if (e >= WP_TOT) return;
  float v;
  if (e < WP_W1_0) {
    int tap = e / 2048;
    int r2 = e % 2048;
    int mt = r2 / 512;
    int lane = (r2 / 8) & 63;
    int el = e & 7;
    int oc = mt * 16 + (lane & 15);
    int ic = (lane >> 4) * 8 + el;
    v = (ic < 25) ? w_in[((size_t)oc * 25 + ic) * 9 + tap] : 0.f;
  } else if (e < WP_OUT) {
    int r = e - WP_W1_0;
    int layer = r / 36864;  // 0:w1b0 1:w2b0 2:w1b1 3:w2b1
    int r2 = r % 36864;
    int tap = r2 / 4096;
    int c = (r2 / 2048) & 1;
    int mt = (r2 / 512) & 3;
    int lane = (r2 / 8) & 63;
    int el = r2 & 7;
    int oc = mt * 16 + (lane & 15);
    int ic = c * 32 + (lane >> 4) * 8 + el;
    const float* src = (layer & 1) ? w2s : w1s;
    int blk = layer >> 1;
    v = src[(((size_t)blk * 64 + oc) * 64 + ic) * 9 + tap];
  } else {
    int r2 = e - WP_OUT;
    int tap = r2 / 1024;
    int c = (r2 / 512) & 1;
    int lane = (r2 / 8) & 63;
    int el = r2 & 7;
    int oc = lane & 15;
    int ic = c * 32 + (lane >> 4) * 8 + el;
    v = (oc < 9) ? w_out[((size_t)oc * 64 + ic) * 9 + tap] : 0.f;
  }
  wp[e] = __float2bfloat16(v);
}

// ---------------------------------------------------------------------------
// conv64 "lite": grid (BT, 8) 4-row strips; 256 thr (4 waves); LDS 26.1 KB
// -> 6 blocks/CU by LDS, ~5 by VGPR => ~20 waves/CU. Wave = 1 output row
// (32 px x 64 oc, acc[4][2] = 16 VGPR). Coalesced store via dead-tile
// transpose (r9/r14-proven). RESID is a coalesced global RMW in the store.
// ---------------------------------------------------------------------------
template <bool SILU, bool RESID>
__global__ __launch_bounds__(256) void conv64_l(
    const __hip_bfloat16* __restrict__ in,   // [512][1024][64] px-major
    const __hip_bfloat16* __restrict__ wpf,  // [9][2][4][64][8]
    const float* __restrict__ bias,          // [64]
    __hip_bfloat16* __restrict__ out) {      // [512][1024][64]
  __shared__ __align__(16) char sT[LTILE];

  const int img = blockIdx.x;
  const int R0 = blockIdx.y * 4;
  const int tid = threadIdx.x;
  const int lane = tid & 63, wv = tid >> 6, g = lane >> 4, ln = lane & 15;
  const size_t imgBase = (size_t)img * HW * 64;

  // ---- stage rows R0-1..R0+4 (6 site-rows, zero-padded halo, swizzled) ----
  for (int e = tid; e < 1632; e += 256) {
    int srow = e / 272;
    int rem = e - srow * 272;
    int sx = rem >> 3, slot = rem & 7;
    int gy = R0 - 1 + srow, gx = sx - 1;
    int4 v = int4{0, 0, 0, 0};
    if (((unsigned)gy < 32u) & ((unsigned)gx < 32u))
      v = *(const int4*)(in + imgBase + (size_t)(gy * 32 + gx) * 64 + slot * 8);
    int dst = (srow * 34 + sx) * 128 + ((slot * 16) ^ ((sx & 7) << 4));
    *(int4*)(sT + dst) = v;
  }
  __syncthreads();

  // swizzled read bases (r8-proven)
  int base[3][2];
#pragma unroll
  for (int d = 0; d < 3; ++d)
#pragma unroll
    for (int c = 0; c < 2; ++c)
      base[d][c] = (((ln + d) * 128 + c * 64 + g * 16) ^ (((ln + d) & 7) << 4));

  // ---- compute: wave wv -> output row R0+wv (reads staged rows wv..wv+2) ----
  f32x4 acc[4][2];
#pragma unroll
  for (int mt = 0; mt < 4; ++mt)
#pragma unroll
    for (int xh = 0; xh < 2; ++xh) acc[mt][xh] = (f32x4)0.f;

  {
    const char* tb = sT + wv * SR;
#pragma unroll
    for (int c = 0; c < 2; ++c)
#pragma unroll
      for (int d = 0; d < 3; ++d) {
        bf16x8 bv[3][2];
#pragma unroll
        for (int dyi = 0; dyi < 3; ++dyi)
#pragma unroll
          for (int xh = 0; xh < 2; ++xh)
            bv[dyi][xh] =
                *(const bf16x8*)(tb + dyi * SR + base[d][c] + xh * 2048);
#pragma unroll
        for (int mt = 0; mt < 4; ++mt)
#pragma unroll
          for (int dyi = 0; dyi < 3; ++dyi) {
            bf16x8 av = *(const bf16x8*)(wpf +
                                         ((((dyi * 3 + d) * 2 + c) * 4 + mt) *
                                              64 +
                                          lane) *
                                             8);
#pragma unroll
            for (int xh = 0; xh < 2; ++xh)
              acc[mt][xh] = __builtin_amdgcn_mfma_f32_16x16x32_bf16(
                  av, bv[dyi][xh], acc[mt][xh], 0, 0, 0);
          }
      }
  }
  __syncthreads();  // tile fully consumed -> reuse as transpose scratch

  // ---- acc (+bias, act) -> tile row wv as [site=px][128B oc], swizzled ----
  {
    const int key = (ln & 7) << 4;
#pragma unroll
    for (int mt = 0; mt < 4; ++mt) {
      const float4 b4 = *(const float4*)(bias + mt * 16 + g * 4);
#pragma unroll
      for (int xh = 0; xh < 2; ++xh) {
        float v0 = acc[mt][xh][0] + b4.x;
        float v1 = acc[mt][xh][1] + b4.y;
        float v2 = acc[mt][xh][2] + b4.z;
        float v3 = acc[mt][xh][3] + b4.w;
        if (SILU) {
          v0 = v0 / (1.f + expf(-v0));
          v1 = v1 / (1.f + expf(-v1));
          v2 = v2 / (1.f + expf(-v2));
          v3 = v3 / (1.f + expf(-v3));
        }
        ushort4 s;
        s.x = f2bs(v0);
        s.y = f2bs(v1);
        s.z = f2bs(v2);
        s.w = f2bs(v3);
        const int site = xh * 16 + ln;
        *(ushort4*)(sT + wv * SR + site * 128 + ((mt * 32 + g * 8) ^ key)) = s;
      }
    }
  }
  __syncthreads();

  // ---- coalesced store: 4 rows x 32 px x 128 B; 64 B per thread ----
  {
    const int row = tid >> 6;
    const int rem = tid & 63;
    const int px = rem >> 1, half = rem & 1;
    const int key = (px & 7) << 4;
    const char* sp = sT + row * SR + px * 128;
    int4 v[4];
#pragma unroll
    for (int q = 0; q < 4; ++q)
      v[q] = *(const int4*)(sp + (((half * 4 + q) * 16) ^ key));
    const int grow = R0 + row;
    char* op =
        (char*)(out + imgBase + (size_t)(grow * 32 + px) * 64 + half * 32);
    if (RESID) {
#pragma unroll
      for (int q = 0; q < 4; ++q) {
        int4 hv = *(const int4*)(op + q * 16);
        ushort ru[8], hu[8];
        __builtin_memcpy(ru, &v[q], 16);
        __builtin_memcpy(hu, &hv, 16);
        ushort ov[8];
#pragma unroll
        for (int i2 = 0; i2 < 8; ++i2) ov[i2] = f2bs(bs2f(ru[i2]) + bs2f(hu[i2]));
        __builtin_memcpy(&v[q], ov, 16);
      }
    }
#pragma unroll
    for (int q = 0; q < 4; ++q) *(int4*)(op + q * 16) = v[q];
  }
}

// ---------------------------------------------------------------------------
// conv_in: prep fused into staging (round-8 proven). grid (BT,4), 256 thr.
// ---------------------------------------------------------------------------
__global__ __launch_bounds__(256) void conv_in_t(
    const float* __restrict__ latents, const int* __restrict__ idx,
    const __hip_bfloat16* __restrict__ wpf, const float* __restrict__ bias,
    __hip_bfloat16* __restrict__ out) {
  __shared__ __align__(16) char sBuf[TILE32];

  const int img = blockIdx.x;
  const int R0 = blockIdx.y * 8;
  const int tid = threadIdx.x;
  const int lane = tid & 63, wv = tid >> 6, g = lane >> 4, ln = lane & 15;
  const int r0L = wv * 2;
  const int b = img >> 7, t = img & 127;

  int t0, t1;
  float ar, a;
  interp_params(idx, b, t, t0, t1, ar, a);
  const float* z0p = latents + ((size_t)b * T + t0) * C * HW;
  const float* z1p = latents + ((size_t)b * T + t1) * C * HW;
  const ushort ab = f2bs(a);

  for (int e = tid; e < 340; e += 256) {
    int srow = e / 34, sx = e - srow * 34;
    int gy = R0 - 1 + srow, gx = sx - 1;
    char* sp = sBuf + srow * SROW32 + sx * 64;
    const int key = (sx & 3) << 4;
    if (((unsigned)gy < 32u) & ((unsigned)gx < 32u)) {
      int p = gy * 32 + gx;
      float v0[8], v1[8];
#pragma unroll
      for (int c2 = 0; c2 < 8; ++c2) {
        v0[c2] = z0p[c2 * HW + p];
        v1[c2] = z1p[c2 * HW + p];
      }
      ushort u[8];
      int4 q;
#pragma unroll
      for (int c2 = 0; c2 < 8; ++c2) u[c2] = f2bs((1.f - a) * v0[c2] + a * v1[c2]);
      q.x = (int)u[0] | ((int)u[1] << 16); q.y = (int)u[2] | ((int)u[3] << 16);
      q.z = (int)u[4] | ((int)u[5] << 16); q.w = (int)u[6] | ((int)u[7] << 16);
      *(int4*)(sp + (0 ^ key)) = q;
#pragma unroll
      for (int c2 = 0; c2 < 8; ++c2) u[c2] = f2bs(v0[c2]);
      q.x = (int)u[0] | ((int)u[1] << 16); q.y = (int)u[2] | ((int)u[3] << 16);
      q.z = (int)u[4] | ((int)u[5] << 16); q.w = (int)u[6] | ((int)u[7] << 16);
      *(int4*)(sp + (16 ^ key)) = q;
#pragma unroll
      for (int c2 = 0; c2 < 8; ++c2) u[c2] = f2bs(v1[c2]);
      q.x = (int)u[0] | ((int)u[1] << 16); q.y = (int)u[2] | ((int)u[3] << 16);
      q.z = (int)u[4] | ((int)u[5] << 16); q.w = (int)u[6] | ((int)u[7] << 16);
      *(int4*)(sp + (32 ^ key)) = q;
      q.x = (int)ab; q.y = 0; q.z = 0; q.w = 0;
      *(int4*)(sp + (48 ^ key)) = q;
    } else {
      int4 z = int4{0, 0, 0, 0};
#pragma unroll
      for (int sl = 0; sl < 4; ++sl) *(int4*)(sp + ((sl * 16) ^ key)) = z;
    }
  }
  __syncthreads();

  int base[3];
#pragma unroll
  for (int d = 0; d < 3; ++d)
    base[d] = r0L * SROW32 + (((ln + d) * 64 + g * 16) ^ (((ln + d) & 3) << 4));

  f32x4 acc[4][4];
#pragma unroll
  for (int mt = 0; mt < 4; ++mt)
#pragma unroll
    for (int nt = 0; nt < 4; ++nt) acc[mt][nt] = (f32x4)0.f;

#pragma unroll
  for (int d = 0; d < 3; ++d) {
    bf16x8 bv[4][2];
#pragma unroll
    for (int j = 0; j < 4; ++j)
#pragma unroll
      for (int xh = 0; xh < 2; ++xh)
        bv[j][xh] = *(const bf16x8*)(sBuf + base[d] + xh * 1024 + j * SROW32);
#pragma unroll
    for (int mt = 0; mt < 4; ++mt)
#pragma unroll
      for (int dyi = 0; dyi < 3; ++dyi) {
        const int tap = dyi * 3 + d;
        bf16x8 av = *(const bf16x8*)(wpf + ((tap * 4 + mt) * 64 + lane) * 8);
#pragma unroll
        for (int oy = 0; oy < 2; ++oy)
#pragma unroll
          for (int xh = 0; xh < 2; ++xh)
            acc[mt][oy * 2 + xh] = __builtin_amdgcn_mfma_f32_16x16x32_bf16(
                av, bv[oy + dyi][xh], acc[mt][oy * 2 + xh], 0, 0, 0);
      }
  }

  const size_t imgBase = (size_t)img * HW * 64;
#pragma unroll
  for (int mt = 0; mt < 4; ++mt) {
    const float4 bv4 = *(const float4*)(bias + mt * 16 + g * 4);
#pragma unroll
    for (int nt = 0; nt < 4; ++nt) {
      const int px = (R0 + r0L + (nt >> 1)) * 32 + (nt & 1) * 16 + ln;
      float v0 = acc[mt][nt][0] + bv4.x;
      float v1 = acc[mt][nt][1] + bv4.y;
      float v2 = acc[mt][nt][2] + bv4.z;
      float v3 = acc[mt][nt][3] + bv4.w;
      ushort4 sv;
      sv.x = f2bs(v0 / (1.f + expf(-v0)));
      sv.y = f2bs(v1 / (1.f + expf(-v1)));
      sv.z = f2bs(v2 / (1.f + expf(-v2)));
      sv.w = f2bs(v3 / (1.f + expf(-v3)));
      *(ushort4*)(out + imgBase + (size_t)px * 64 + mt * 16 + g * 4) = sv;
    }
  }
}

// ---------------------------------------------------------------------------
// final conv (64->16, 9 real) fused with z_hat / conf epilogue (round 8).
// ---------------------------------------------------------------------------
__global__ __launch_bounds__(256) void conv_final_t(
    const __hip_bfloat16* __restrict__ in, const __hip_bfloat16* __restrict__ wpf,
    const float* __restrict__ bias, const float* __restrict__ latents,
    const int* __restrict__ idx, float* __restrict__ dout) {
  __shared__ __align__(16) char sBuf[TILE64];
  __shared__ float sOut[256][17];

  const int img = blockIdx.x;
  const int R0 = blockIdx.y * 8;
  const int tid = threadIdx.x;
  const int lane = tid & 63, wv = tid >> 6, g = lane >> 4, ln = lane & 15;
  const int r0L = wv * 2;
  const int b = img >> 7, t = img & 127;
  const size_t imgBase = (size_t)img * HW * 64;

  int t0, t1;
  float ar, a;
  interp_params(idx, b, t, t0, t1, ar, a);
  const float* z0p = latents + ((size_t)b * T + t0) * C * HW;
  const float* z1p = latents + ((size_t)b * T + t1) * C * HW;

  for (int e = tid; e < 2720; e += 256) {
    int srow = e / 272;
    int rem = e - srow * 272;
    int sx = rem >> 3, slot = rem & 7;
    int gy = R0 - 1 + srow, gx = sx - 1;
    int4 v = int4{0, 0, 0, 0};
    if (((unsigned)gy < 32u) & ((unsigned)gx < 32u))
      v = *(const int4*)(in + imgBase + (size_t)(gy * 32 + gx) * 64 + slot * 8);
    int dst = (srow * 34 + sx) * 128 + ((slot * 16) ^ ((sx & 7) << 4));
    *(int4*)(sBuf + dst) = v;
  }
  __syncthreads();

  int base[3][2];
#pragma unroll
  for (int d = 0; d < 3; ++d)
#pragma unroll
    for (int c = 0; c < 2; ++c)
      base[d][c] = r0L * SR +
                   (((ln + d) * 128 + c * 64 + g * 16) ^ (((ln + d) & 7) << 4));

  f32x4 acc[4];
#pragma unroll
  for (int nt = 0; nt < 4; ++nt) acc[nt] = (f32x4)0.f;

#pragma unroll
  for (int c = 0; c < 2; ++c)
#pragma unroll
    for (int d = 0; d < 3; ++d) {
      bf16x8 bv[4][2];
#pragma unroll
      for (int j = 0; j < 4; ++j)
#pragma unroll
        for (int xh = 0; xh < 2; ++xh)
          bv[j][xh] = *(const bf16x8*)(sBuf + base[d][c] + xh * 2048 + j * SR);
#pragma unroll
      for (int dyi = 0; dyi < 3; ++dyi) {
        const int tap = dyi * 3 + d;
        bf16x8 av = *(const bf16x8*)(wpf + ((tap * 2 + c) * 64 + lane) * 8);
#pragma unroll
        for (int oy = 0; oy < 2; ++oy)
#pragma unroll
          for (int xh = 0; xh < 2; ++xh)
            acc[oy * 2 + xh] = __builtin_amdgcn_mfma_f32_16x16x32_bf16(
                av, bv[oy + dyi][xh], acc[oy * 2 + xh], 0, 0, 0);
      }
    }

#pragma unroll
  for (int nt = 0; nt < 4; ++nt) {
    const int pxl = (r0L + (nt >> 1)) * 32 + (nt & 1) * 16 + ln;
#pragma unroll
    for (int r = 0; r < 4; ++r) {
      const int oc = g * 4 + r;
      sOut[pxl][oc] = acc[nt][r] + ((oc < 9) ? bias[oc] : 0.f);
    }
  }
  __syncthreads();

  const bool interior = (ar > 0.f) && (ar < 1.f);
  const float aa = a * (1.f - a);
  const int px = R0 * 32 + tid;
#pragma unroll
  for (int c2 = 0; c2 < 8; ++c2) {
    float res = sOut[tid][c2];
    float v0 = z0p[c2 * HW + px], v1 = z1p[c2 * HW + px];
    float zb = (1.f - a) * v0 + a * v1;
    dout[((size_t)img * C + c2) * HW + px] = zb + aa * res;
  }
  float unc = 1.f / (1.f + expf(-sOut[tid][8]));
  float conf = interior ? fminf(fmaxf(1.f - unc, 0.f), 1.f) : 1.f;
  dout[Z_SIZE + (size_t)img * HW + px] = conf;
}

// ---------------------------------------------------------------------------
extern "C" void kernel_launch(void* const* d_in, const int* in_sizes, int n_in,
                              void* d_out, int out_size, void* d_ws,
                              size_t ws_size, hipStream_t stream) {
  const float* latents = (const float*)d_in[0];
  const int* idx = (const int*)d_in[1];
  const float* w_in = (const float*)d_in[2];
  const float* b_in = (const float*)d_in[3];
  const float* w1s = (const float*)d_in[4];
  const float* b1s = (const float*)d_in[5];
  const float* w2s = (const float*)d_in[6];
  const float* b2s = (const float*)d_in[7];
  const float* w_out = (const float*)d_in[8];
  const float* b_out = (const float*)d_in[9];
  float* dout = (float*)d_out;

  char* ws = (char*)d_ws;
  __hip_bfloat16* A = (__hip_bfloat16*)ws;                        // 64 MiB
  __hip_bfloat16* Bb = (__hip_bfloat16*)(ws + (size_t)67108864);  // 64 MiB
  __hip_bfloat16* wpk = (__hip_bfloat16*)(ws + (size_t)134217728);

  pack_weights<<<(WP_TOT + 255) / 256, 256, 0, stream>>>(w_in, w1s, w2s, w_out,
                                                         wpk);

  conv_in_t<<<dim3(BT, 4), 256, 0, stream>>>(latents, idx, wpk + WP_IN, b_in,
                                             A);

  dim3 grid8(BT, 8);
  conv64_l<true, false><<<grid8, 256, 0, stream>>>(A, wpk + WP_W1_0, b1s, Bb);
  conv64_l<false, true><<<grid8, 256, 0, stream>>>(Bb, wpk + WP_W2_0, b2s, A);
  conv64_l<true, false><<<grid8, 256, 0, stream>>>(A, wpk + WP_W1_1, b1s + 64,
                                                   Bb);
  conv64_l<false, true><<<grid8, 256, 0, stream>>>(Bb, wpk + WP_W2_1, b2s + 64,
                                                   A);

  conv_final_t<<<dim3(BT, 4), 256, 0, stream>>>(A, wpk + WP_OUT, b_out, latents,
                                                idx, dout);
}